// Round 17
// baseline (441.243 us; speedup 1.0000x reference)
//
#include <hip/hip_runtime.h>
#include <hip/hip_bf16.h>
#include <stdint.h>

#define B_SZ 4
#define L_SEQ 2048
#define EMB 2048
#define NH 16
#define HD 128
#define BLROWS (B_SZ * L_SEQ)   // 8192
#define BK 32

typedef __bf16 bf16;
typedef __bf16 bf16x8 __attribute__((ext_vector_type(8)));
typedef __bf16 bf16x4 __attribute__((ext_vector_type(4)));
typedef float f32x4 __attribute__((ext_vector_type(4)));

#define MFMA16(A, Bv, C) __builtin_amdgcn_mfma_f32_16x16x32_bf16(A, Bv, C, 0, 0, 0)

__device__ __forceinline__ void gll16(bf16* l, const bf16* g) {
  __builtin_amdgcn_global_load_lds(
      (const __attribute__((address_space(1))) unsigned int*)g,
      (__attribute__((address_space(3))) unsigned int*)l, 16, 0, 0);
}

// ---------------- all fp32 -> bf16 conversions, one launch ----------------
__global__ __launch_bounds__(256) void f2bAll_kernel(
    const float* __restrict__ x, const float* __restrict__ w0,
    const float* __restrict__ w1, const float* __restrict__ w2,
    const float* __restrict__ w3, bf16* __restrict__ ox, bf16* __restrict__ o0,
    bf16* __restrict__ o1, bf16* __restrict__ o2, bf16* __restrict__ o3,
    int nx4, int nw4) {
  const int y = blockIdx.y;
  const float* in = (y == 0) ? x : (y == 1) ? w0 : (y == 2) ? w1
                    : (y == 3) ? w2 : w3;
  bf16* out = (y == 0) ? ox : (y == 1) ? o0 : (y == 2) ? o1
              : (y == 3) ? o2 : o3;
  const int n4 = (y == 0) ? nx4 : nw4;
  int i = blockIdx.x * blockDim.x + threadIdx.x;
  int stride = gridDim.x * blockDim.x;
  for (; i < n4; i += stride) {
    float4 v = ((const float4*)in)[i];
    bf16x4 o = {(bf16)v.x, (bf16)v.y, (bf16)v.z, (bf16)v.w};
    ((bf16x4*)out)[i] = o;
  }
}

// ------- 256xBNT GEMM, BK=32, 3-stage counted-vmcnt pipeline ---------------
// Grouped raster: XCD x (bx&7) owns a 4-bm x all-bn rectangle -> per-XCD A
// working set 4MB (L2-resident). (round-11/13 proven: QKV 200us, FETCH 148MB)
template <int EPI, int BNT>
__global__ __launch_bounds__(512, 2) void gemm256(const bf16* __restrict__ A,
                                                  const bf16* __restrict__ Bm,
                                                  bf16* __restrict__ Cq,
                                                  bf16* __restrict__ Ck,
                                                  bf16* __restrict__ Cvt,
                                                  float* __restrict__ Cf,
                                                  int K) {
  constexpr int NB = BNT / 64;
  __shared__ bf16 Abuf[3][256 * BK];
  __shared__ bf16 Bbuf[3][BNT * BK];
  const int tid = threadIdx.x, lane = tid & 63, w = tid >> 6;
  const int wr = w >> 2, wc = w & 3;
  const int l15 = lane & 15;

  const int bx = blockIdx.x;
  const int bm = ((bx & 7) * 4 + ((bx >> 3) & 3)) * 256;
  const int bn = (bx >> 5) * BNT;
  const int NT = K / BK;

  const int idA0 = tid, idA1 = 512 + tid;
  const int ar0 = idA0 >> 2, ar1 = idA1 >> 2;
  const size_t aS0 = (size_t)(bm + ar0) * K + (((idA0 & 3) ^ ((ar0 >> 1) & 3)) * 8);
  const size_t aS1 = (size_t)(bm + ar1) * K + (((idA1 & 3) ^ ((ar1 >> 1) & 3)) * 8);
  const size_t bS0 = (size_t)(bn + ar0) * K + (((idA0 & 3) ^ ((ar0 >> 1) & 3)) * 8);
  const size_t bS1 = (size_t)(bn + ar1) * K + (((idA1 & 3) ^ ((ar1 >> 1) & 3)) * 8);
  const int ldsD0 = idA0 * 8, ldsD1 = idA1 * 8;

  const int eSw = ((lane >> 4) * 8) ^ (((l15 >> 1) & 3) << 3);
  int aoff[8], boff[NB];
#pragma unroll
  for (int m = 0; m < 8; m++) aoff[m] = (wr * 128 + m * 16 + l15) * BK + eSw;
#pragma unroll
  for (int n = 0; n < NB; n++) boff[n] = (wc * (BNT / 4) + n * 16 + l15) * BK + eSw;

  f32x4 acc[8][NB] = {};

  gll16(&Abuf[0][ldsD0], A + aS0);
  gll16(&Bbuf[0][ldsD0], Bm + bS0);
  gll16(&Abuf[0][ldsD1], A + aS1);
  if constexpr (BNT == 256) gll16(&Bbuf[0][ldsD1], Bm + bS1);
  gll16(&Abuf[1][ldsD0], A + aS0 + BK);
  gll16(&Bbuf[1][ldsD0], Bm + bS0 + BK);
  gll16(&Abuf[1][ldsD1], A + aS1 + BK);
  if constexpr (BNT == 256) gll16(&Bbuf[1][ldsD1], Bm + bS1 + BK);
  if constexpr (BNT == 256)
    asm volatile("s_waitcnt vmcnt(4)" ::: "memory");
  else
    asm volatile("s_waitcnt vmcnt(3)" ::: "memory");
  __builtin_amdgcn_s_barrier();
  asm volatile("" ::: "memory");

  int cur = 0, nxt = 2;
  for (int kt = 0; kt < NT; ++kt) {
    const bf16* __restrict__ Ab = Abuf[cur];
    const bf16* __restrict__ Bb = Bbuf[cur];
    const bool pre = (kt + 2 < NT);
    const size_t k2 = (size_t)(kt + 2) * BK;

    bf16x8 af[8], bq[NB];
#pragma unroll
    for (int m = 0; m < 8; m++) af[m] = *(const bf16x8*)&Ab[aoff[m]];
    bq[0] = *(const bf16x8*)&Bb[boff[0]];
    if constexpr (NB > 2) bq[1] = *(const bf16x8*)&Bb[boff[1]];
    if (pre) {
      gll16(&Abuf[nxt][ldsD0], A + aS0 + k2);
      gll16(&Bbuf[nxt][ldsD0], Bm + bS0 + k2);
    }
    asm volatile("s_waitcnt lgkmcnt(0)" ::: "memory");
    __builtin_amdgcn_sched_barrier(0);
    __builtin_amdgcn_s_setprio(1);
#pragma unroll
    for (int m = 0; m < 8; m++) acc[m][0] = MFMA16(af[m], bq[0], acc[m][0]);
    if constexpr (NB > 2) {
#pragma unroll
      for (int m = 0; m < 8; m++) acc[m][1] = MFMA16(af[m], bq[1], acc[m][1]);
    }
    __builtin_amdgcn_s_setprio(0);

    constexpr int n2 = (NB > 2) ? 2 : 1;
    bf16x8 b2 = *(const bf16x8*)&Bb[boff[n2]];
    bf16x8 b3;
    if constexpr (NB > 2) b3 = *(const bf16x8*)&Bb[boff[3]];
    if (pre) {
      gll16(&Abuf[nxt][ldsD1], A + aS1 + k2);
      if constexpr (BNT == 256) gll16(&Bbuf[nxt][ldsD1], Bm + bS1 + k2);
    }
    asm volatile("s_waitcnt lgkmcnt(0)" ::: "memory");
    __builtin_amdgcn_sched_barrier(0);
    __builtin_amdgcn_s_setprio(1);
#pragma unroll
    for (int m = 0; m < 8; m++) acc[m][n2] = MFMA16(af[m], b2, acc[m][n2]);
    if constexpr (NB > 2) {
#pragma unroll
      for (int m = 0; m < 8; m++) acc[m][3] = MFMA16(af[m], b3, acc[m][3]);
    }
    __builtin_amdgcn_s_setprio(0);

    if (kt < NT - 1) {
      if (pre) {
        if constexpr (BNT == 256)
          asm volatile("s_waitcnt vmcnt(4)" ::: "memory");
        else
          asm volatile("s_waitcnt vmcnt(3)" ::: "memory");
      } else {
        asm volatile("s_waitcnt vmcnt(0)" ::: "memory");
      }
      __builtin_amdgcn_s_barrier();
      asm volatile("" ::: "memory");
    }
    cur = (cur == 2) ? 0 : cur + 1;
    nxt = (nxt == 2) ? 0 : nxt + 1;
  }

  const int grow0 = bm + wr * 128 + (lane >> 4) * 4;
  const int gcol0 = bn + wc * (BNT / 4) + l15;
#pragma unroll
  for (int i = 0; i < 8; i++)
#pragma unroll
    for (int j = 0; j < NB; j++) {
      int grow = grow0 + i * 16;
      int gcol = gcol0 + j * 16;
      if (EPI == 1) {
#pragma unroll
        for (int r = 0; r < 4; r++)
          Cf[(size_t)(grow + r) * 2048 + gcol] = acc[i][j][r];
      } else {
        int mat = gcol >> 11, mcol = gcol & 2047;
        if (mat == 2) {
          int b = grow >> 11;
          bf16x4 pk = {(bf16)acc[i][j][0], (bf16)acc[i][j][1],
                       (bf16)acc[i][j][2], (bf16)acc[i][j][3]};
          *(bf16x4*)&Cvt[((size_t)(b * 2048 + mcol)) * 2048 + (grow & 2047)] = pk;
        } else {
          bf16* Cp = (mat == 0) ? Cq : Ck;
#pragma unroll
          for (int r = 0; r < 4; r++)
            Cp[(size_t)(grow + r) * 2048 + mcol] = (bf16)acc[i][j][r];
        }
      }
    }
}

// ---------------- fused RMSNorm + RoPE for Q and K, one launch -------------
__global__ __launch_bounds__(256) void normrope2_kernel(bf16* __restrict__ Tq,
                                                        bf16* __restrict__ Tk,
                                                        const float* __restrict__ wq,
                                                        const float* __restrict__ wk,
                                                        const float* __restrict__ cs,
                                                        const float* __restrict__ sn) {
  bf16* T = blockIdx.y ? Tk : Tq;
  const float* w = blockIdx.y ? wk : wq;
  int row = blockIdx.x * 4 + (threadIdx.x >> 6);
  int lane = threadIdx.x & 63;
  int bl = row >> 4;
  int h = row & 15;
  bf16* p = T + (size_t)bl * EMB + h * HD;
  float v1 = (float)p[lane];
  float v2 = (float)p[lane + 64];
  float ss = v1 * v1 + v2 * v2;
#pragma unroll
  for (int m = 32; m; m >>= 1) ss += __shfl_xor(ss, m, 64);
  float r = rsqrtf(ss * (1.0f / 128.0f) + 1e-6f);
  float n1 = v1 * r * w[lane];
  float n2 = v2 * r * w[lane + 64];
  float c = cs[(size_t)bl * 64 + lane];
  float s = sn[(size_t)bl * 64 + lane];
  p[lane]      = (bf16)(n1 * c - n2 * s);
  p[lane + 64] = (bf16)(n1 * s + n2 * c);
}

// ---- causal flash attention: 16 waves x 256 q-rows, swapped QK^T ----------
// Round-16 structure with one more amortization doubling: one block stages
// each K/V tile for 256 q-rows (16 waves x 16 rows). Staging traffic and
// vmcnt/barrier events per unit work drop another 1.89x. Per-wave code is
// byte-identical. 96 KB LDS -> 1 block/CU x 16 waves = 4 waves/SIMD (same
// resident-wave count as round-16's 2x8). Staging = exactly 1 chunk/thread.
__device__ __forceinline__ void stage_kv16(bf16* Ksb, bf16* Vsb,
                                           const bf16* gK, const bf16* gV,
                                           int kt, int tid) {
  int kr = tid >> 4, kc = tid & 15;
  gll16(&Ksb[tid * 8], gK + (size_t)(kt * 64 + kr) * EMB + ((kc ^ (kr & 7)) * 8));
  int dr = tid >> 3, vc = tid & 7;
  gll16(&Vsb[tid * 8], gV + (size_t)dr * L_SEQ + kt * 64 + ((vc ^ (dr & 7)) * 8));
}

__global__ __launch_bounds__(1024, 1) void fattn_kernel(const bf16* __restrict__ Q,
                                                        const bf16* __restrict__ K,
                                                        const bf16* __restrict__ Vt,
                                                        bf16* __restrict__ AO) {
  __shared__ bf16 Ks[2][64 * 128];    // 32 KB
  __shared__ bf16 Vs[2][64 * 128];    // 32 KB
  __shared__ bf16 Ps[16 * 16 * 64];   // 32 KB, wave-private
  const int tid = threadIdx.x, lane = tid & 63, w = tid >> 6;
  const int l15 = lane & 15, grp = lane >> 4;

  int id = blockIdx.x + blockIdx.y * 8;      // grid (8, 64)
  int bh = id & 63;
  int qt = 7 - (id >> 6);                    // heavy q-tiles first
  const int b = bh >> 4, h = bh & 15;
  const size_t base = (size_t)b * L_SEQ * EMB + h * HD;
  const bf16* gK = K + base;
  const bf16* gV = Vt + (size_t)(b * NH + h) * HD * L_SEQ;
  const int qrow0 = qt * 256 + w * 16;       // wave's 16 q-rows
  const int q_own = qrow0 + l15;

  const float a_ = 0.08838834764831845f * 1.4426950408889634f;
  const float b_ = 12.0f * 1.4426950408889634f;

  bf16x8 qf[4];
  {
    const bf16* qp = Q + base + (size_t)(qrow0 + l15) * EMB + (grp * 8);
#pragma unroll
    for (int c = 0; c < 4; c++) qf[c] = *(const bf16x8*)(qp + c * 32);
  }

  f32x4 O[8] = {};
  float lsum_p = 0.f;
  bf16* myP = Ps + w * 1024;
  const int pwbase = l15 * 64 + (grp & 1) * 4;
  const int c8base = grp >> 1;

  const int nkt = 4 * qt + 4;
  stage_kv16(Ks[0], Vs[0], gK, gV, 0, tid);
  asm volatile("s_waitcnt vmcnt(0)" ::: "memory");
  __builtin_amdgcn_s_barrier();
  asm volatile("" ::: "memory");

  for (int kt = 0; kt < nkt; kt++) {
    const int cur = kt & 1;
    if (kt + 1 < nkt) stage_kv16(Ks[cur ^ 1], Vs[cur ^ 1], gK, gV, kt + 1, tid);

    if (kt * 64 <= qrow0 + 15) {   // wave-uniform gate
      // S^T = K Q^T
      f32x4 st[4] = {};
      __builtin_amdgcn_s_setprio(1);
#pragma unroll
      for (int s = 0; s < 4; s++) {
        int row = s * 16 + l15;
#pragma unroll
        for (int c = 0; c < 4; c++) {
          int swc = (c * 4 + grp) ^ (row & 7);
          bf16x8 kf = *(const bf16x8*)&Ks[cur][row * 128 + swc * 8];
          st[s] = MFMA16(kf, qf[c], st[s]);
        }
      }
      __builtin_amdgcn_s_setprio(0);

      // bounded-exp P, packed b64 write (mask always)
#pragma unroll
      for (int s = 0; s < 4; s++) {
        float e[4];
#pragma unroll
        for (int r = 0; r < 4; r++) {
          int kg = kt * 64 + s * 16 + grp * 4 + r;
          float v = exp2f(st[s][r] * a_ - b_);
          if (kg > q_own) v = 0.f;
          e[r] = v;
          lsum_p += v;
        }
        bf16x4 pk = {(bf16)e[0], (bf16)e[1], (bf16)e[2], (bf16)e[3]};
        int c8 = s * 2 + c8base;
        *(bf16x4*)&myP[pwbase + ((c8 ^ (l15 & 7)) << 3)] = pk;
      }

      // P read + PV (round-13 proven path)
      bf16x8 pf[2];
#pragma unroll
      for (int kk = 0; kk < 2; kk++) {
        int swc = (kk * 4 + grp) ^ (l15 & 7);
        pf[kk] = *(const bf16x8*)&myP[l15 * 64 + swc * 8];
      }
      __builtin_amdgcn_s_setprio(1);
#pragma unroll
      for (int ni = 0; ni < 8; ni++) {
#pragma unroll
        for (int kk = 0; kk < 2; kk++) {
          int drow = ni * 16 + l15;
          int swc = (kk * 4 + grp) ^ (drow & 7);
          bf16x8 vf = *(const bf16x8*)&Vs[cur][drow * 64 + swc * 8];
          O[ni] = MFMA16(pf[kk], vf, O[ni]);
        }
      }
      __builtin_amdgcn_s_setprio(0);
    }

    asm volatile("s_waitcnt vmcnt(0)" ::: "memory");
    __builtin_amdgcn_s_barrier();
    asm volatile("" ::: "memory");
  }

  // row-sum: reduce partials over the 4 grp lanes, then fetch per output row
  lsum_p += __shfl_xor(lsum_p, 16, 64);
  lsum_p += __shfl_xor(lsum_p, 32, 64);
  float lr[4];
#pragma unroll
  for (int r = 0; r < 4; r++) lr[r] = __shfl(lsum_p, grp * 4 + r, 64);

  const int qg0 = qrow0 + grp * 4;
#pragma unroll
  for (int ni = 0; ni < 8; ni++) {
#pragma unroll
    for (int r = 0; r < 4; r++) {
      float o = O[ni][r] / lr[r];
      AO[(size_t)(b * L_SEQ + qg0 + r) * EMB + h * HD + ni * 16 + l15] = (bf16)o;
    }
  }
}

extern "C" void kernel_launch(void* const* d_in, const int* in_sizes, int n_in,
                              void* d_out, int out_size, void* d_ws, size_t ws_size,
                              hipStream_t stream) {
  const float* x = (const float*)d_in[0];
  const float* cosp = (const float*)d_in[2];
  const float* sinp = (const float*)d_in[3];
  const float* Wq = (const float*)d_in[4];
  const float* Wk = (const float*)d_in[5];
  const float* Wv = (const float*)d_in[6];
  const float* Wo = (const float*)d_in[7];
  const float* qw = (const float*)d_in[8];
  const float* kw = (const float*)d_in[9];

  const size_t ACT = (size_t)BLROWS * EMB * sizeof(bf16);
  const size_t WGT = (size_t)EMB * EMB * sizeof(bf16);
  char* ws = (char*)d_ws;
  bf16* xb    = (bf16*)ws;          ws += ACT;
  bf16* WQKVb = (bf16*)ws;          ws += 3 * WGT;
  bf16* Wob   = (bf16*)ws;          ws += WGT;
  bf16* Qb    = (bf16*)ws;          ws += ACT;
  bf16* Kb    = (bf16*)ws;          ws += ACT;
  bf16* Vtb   = (bf16*)ws;          ws += ACT;
  bf16* AOb   = (bf16*)ws;          ws += ACT;

  f2bAll_kernel<<<dim3(512, 5), 256, 0, stream>>>(
      x, Wq, Wk, Wv, Wo, xb, WQKVb, WQKVb + (size_t)EMB * EMB,
      WQKVb + 2 * (size_t)EMB * EMB, Wob, BLROWS * EMB / 4, EMB * EMB / 4);

  gemm256<0, 256><<<768, 512, 0, stream>>>(xb, WQKVb, Qb, Kb, Vtb, nullptr, EMB);

  normrope2_kernel<<<dim3(BLROWS * NH / 4, 2), 256, 0, stream>>>(Qb, Kb, qw, kw,
                                                                 cosp, sinp);

  fattn_kernel<<<dim3(8, B_SZ * NH), 1024, 0, stream>>>(Qb, Kb, Vtb, AOb);

  gemm256<1, 128><<<512, 512, 0, stream>>>(AOb, Wob, nullptr, nullptr, nullptr,
                                           (float*)d_out, EMB);
}

// Round 18
// 429.256 us; speedup vs baseline: 1.0279x; 1.0279x over previous
//
#include <hip/hip_runtime.h>
#include <hip/hip_bf16.h>
#include <stdint.h>

#define B_SZ 4
#define L_SEQ 2048
#define EMB 2048
#define NH 16
#define HD 128
#define BLROWS (B_SZ * L_SEQ)   // 8192
#define BK 32

typedef __bf16 bf16;
typedef __bf16 bf16x8 __attribute__((ext_vector_type(8)));
typedef __bf16 bf16x4 __attribute__((ext_vector_type(4)));
typedef float f32x4 __attribute__((ext_vector_type(4)));

#define MFMA16(A, Bv, C) __builtin_amdgcn_mfma_f32_16x16x32_bf16(A, Bv, C, 0, 0, 0)

__device__ __forceinline__ void gll16(bf16* l, const bf16* g) {
  __builtin_amdgcn_global_load_lds(
      (const __attribute__((address_space(1))) unsigned int*)g,
      (__attribute__((address_space(3))) unsigned int*)l, 16, 0, 0);
}

// ---------------- all fp32 -> bf16 conversions, one launch ----------------
__global__ __launch_bounds__(256) void f2bAll_kernel(
    const float* __restrict__ x, const float* __restrict__ w0,
    const float* __restrict__ w1, const float* __restrict__ w2,
    const float* __restrict__ w3, bf16* __restrict__ ox, bf16* __restrict__ o0,
    bf16* __restrict__ o1, bf16* __restrict__ o2, bf16* __restrict__ o3,
    int nx4, int nw4) {
  const int y = blockIdx.y;
  const float* in = (y == 0) ? x : (y == 1) ? w0 : (y == 2) ? w1
                    : (y == 3) ? w2 : w3;
  bf16* out = (y == 0) ? ox : (y == 1) ? o0 : (y == 2) ? o1
              : (y == 3) ? o2 : o3;
  const int n4 = (y == 0) ? nx4 : nw4;
  int i = blockIdx.x * blockDim.x + threadIdx.x;
  int stride = gridDim.x * blockDim.x;
  for (; i < n4; i += stride) {
    float4 v = ((const float4*)in)[i];
    bf16x4 o = {(bf16)v.x, (bf16)v.y, (bf16)v.z, (bf16)v.w};
    ((bf16x4*)out)[i] = o;
  }
}

// ------- 256xBNT GEMM, BK=32, 3-stage counted-vmcnt pipeline ---------------
// Grouped raster: XCD x (bx&7) owns a 4-bm x all-bn rectangle -> per-XCD A
// working set 4MB (L2-resident). (round-11/13 proven: QKV 200us, FETCH 148MB)
template <int EPI, int BNT>
__global__ __launch_bounds__(512, 2) void gemm256(const bf16* __restrict__ A,
                                                  const bf16* __restrict__ Bm,
                                                  bf16* __restrict__ Cq,
                                                  bf16* __restrict__ Ck,
                                                  bf16* __restrict__ Cvt,
                                                  float* __restrict__ Cf,
                                                  int K) {
  constexpr int NB = BNT / 64;
  __shared__ bf16 Abuf[3][256 * BK];
  __shared__ bf16 Bbuf[3][BNT * BK];
  const int tid = threadIdx.x, lane = tid & 63, w = tid >> 6;
  const int wr = w >> 2, wc = w & 3;
  const int l15 = lane & 15;

  const int bx = blockIdx.x;
  const int bm = ((bx & 7) * 4 + ((bx >> 3) & 3)) * 256;
  const int bn = (bx >> 5) * BNT;
  const int NT = K / BK;

  const int idA0 = tid, idA1 = 512 + tid;
  const int ar0 = idA0 >> 2, ar1 = idA1 >> 2;
  const size_t aS0 = (size_t)(bm + ar0) * K + (((idA0 & 3) ^ ((ar0 >> 1) & 3)) * 8);
  const size_t aS1 = (size_t)(bm + ar1) * K + (((idA1 & 3) ^ ((ar1 >> 1) & 3)) * 8);
  const size_t bS0 = (size_t)(bn + ar0) * K + (((idA0 & 3) ^ ((ar0 >> 1) & 3)) * 8);
  const size_t bS1 = (size_t)(bn + ar1) * K + (((idA1 & 3) ^ ((ar1 >> 1) & 3)) * 8);
  const int ldsD0 = idA0 * 8, ldsD1 = idA1 * 8;

  const int eSw = ((lane >> 4) * 8) ^ (((l15 >> 1) & 3) << 3);
  int aoff[8], boff[NB];
#pragma unroll
  for (int m = 0; m < 8; m++) aoff[m] = (wr * 128 + m * 16 + l15) * BK + eSw;
#pragma unroll
  for (int n = 0; n < NB; n++) boff[n] = (wc * (BNT / 4) + n * 16 + l15) * BK + eSw;

  f32x4 acc[8][NB] = {};

  gll16(&Abuf[0][ldsD0], A + aS0);
  gll16(&Bbuf[0][ldsD0], Bm + bS0);
  gll16(&Abuf[0][ldsD1], A + aS1);
  if constexpr (BNT == 256) gll16(&Bbuf[0][ldsD1], Bm + bS1);
  gll16(&Abuf[1][ldsD0], A + aS0 + BK);
  gll16(&Bbuf[1][ldsD0], Bm + bS0 + BK);
  gll16(&Abuf[1][ldsD1], A + aS1 + BK);
  if constexpr (BNT == 256) gll16(&Bbuf[1][ldsD1], Bm + bS1 + BK);
  if constexpr (BNT == 256)
    asm volatile("s_waitcnt vmcnt(4)" ::: "memory");
  else
    asm volatile("s_waitcnt vmcnt(3)" ::: "memory");
  __builtin_amdgcn_s_barrier();
  asm volatile("" ::: "memory");

  int cur = 0, nxt = 2;
  for (int kt = 0; kt < NT; ++kt) {
    const bf16* __restrict__ Ab = Abuf[cur];
    const bf16* __restrict__ Bb = Bbuf[cur];
    const bool pre = (kt + 2 < NT);
    const size_t k2 = (size_t)(kt + 2) * BK;

    bf16x8 af[8], bq[NB];
#pragma unroll
    for (int m = 0; m < 8; m++) af[m] = *(const bf16x8*)&Ab[aoff[m]];
    bq[0] = *(const bf16x8*)&Bb[boff[0]];
    if constexpr (NB > 2) bq[1] = *(const bf16x8*)&Bb[boff[1]];
    if (pre) {
      gll16(&Abuf[nxt][ldsD0], A + aS0 + k2);
      gll16(&Bbuf[nxt][ldsD0], Bm + bS0 + k2);
    }
    asm volatile("s_waitcnt lgkmcnt(0)" ::: "memory");
    __builtin_amdgcn_sched_barrier(0);
    __builtin_amdgcn_s_setprio(1);
#pragma unroll
    for (int m = 0; m < 8; m++) acc[m][0] = MFMA16(af[m], bq[0], acc[m][0]);
    if constexpr (NB > 2) {
#pragma unroll
      for (int m = 0; m < 8; m++) acc[m][1] = MFMA16(af[m], bq[1], acc[m][1]);
    }
    __builtin_amdgcn_s_setprio(0);

    constexpr int n2 = (NB > 2) ? 2 : 1;
    bf16x8 b2 = *(const bf16x8*)&Bb[boff[n2]];
    bf16x8 b3;
    if constexpr (NB > 2) b3 = *(const bf16x8*)&Bb[boff[3]];
    if (pre) {
      gll16(&Abuf[nxt][ldsD1], A + aS1 + k2);
      if constexpr (BNT == 256) gll16(&Bbuf[nxt][ldsD1], Bm + bS1 + k2);
    }
    asm volatile("s_waitcnt lgkmcnt(0)" ::: "memory");
    __builtin_amdgcn_sched_barrier(0);
    __builtin_amdgcn_s_setprio(1);
#pragma unroll
    for (int m = 0; m < 8; m++) acc[m][n2] = MFMA16(af[m], b2, acc[m][n2]);
    if constexpr (NB > 2) {
#pragma unroll
      for (int m = 0; m < 8; m++) acc[m][3] = MFMA16(af[m], b3, acc[m][3]);
    }
    __builtin_amdgcn_s_setprio(0);

    if (kt < NT - 1) {
      if (pre) {
        if constexpr (BNT == 256)
          asm volatile("s_waitcnt vmcnt(4)" ::: "memory");
        else
          asm volatile("s_waitcnt vmcnt(3)" ::: "memory");
      } else {
        asm volatile("s_waitcnt vmcnt(0)" ::: "memory");
      }
      __builtin_amdgcn_s_barrier();
      asm volatile("" ::: "memory");
    }
    cur = (cur == 2) ? 0 : cur + 1;
    nxt = (nxt == 2) ? 0 : nxt + 1;
  }

  const int grow0 = bm + wr * 128 + (lane >> 4) * 4;
  const int gcol0 = bn + wc * (BNT / 4) + l15;
#pragma unroll
  for (int i = 0; i < 8; i++)
#pragma unroll
    for (int j = 0; j < NB; j++) {
      int grow = grow0 + i * 16;
      int gcol = gcol0 + j * 16;
      if (EPI == 1) {
#pragma unroll
        for (int r = 0; r < 4; r++)
          Cf[(size_t)(grow + r) * 2048 + gcol] = acc[i][j][r];
      } else {
        int mat = gcol >> 11, mcol = gcol & 2047;
        if (mat == 2) {
          int b = grow >> 11;
          bf16x4 pk = {(bf16)acc[i][j][0], (bf16)acc[i][j][1],
                       (bf16)acc[i][j][2], (bf16)acc[i][j][3]};
          *(bf16x4*)&Cvt[((size_t)(b * 2048 + mcol)) * 2048 + (grow & 2047)] = pk;
        } else {
          bf16* Cp = (mat == 0) ? Cq : Ck;
#pragma unroll
          for (int r = 0; r < 4; r++)
            Cp[(size_t)(grow + r) * 2048 + mcol] = (bf16)acc[i][j][r];
        }
      }
    }
}

// ---------------- fused RMSNorm + RoPE, K only (Q fused into fattn) --------
__global__ __launch_bounds__(256) void normropeK_kernel(bf16* __restrict__ T,
                                                        const float* __restrict__ w,
                                                        const float* __restrict__ cs,
                                                        const float* __restrict__ sn) {
  int row = blockIdx.x * 4 + (threadIdx.x >> 6);
  int lane = threadIdx.x & 63;
  int bl = row >> 4;
  int h = row & 15;
  bf16* p = T + (size_t)bl * EMB + h * HD;
  float v1 = (float)p[lane];
  float v2 = (float)p[lane + 64];
  float ss = v1 * v1 + v2 * v2;
#pragma unroll
  for (int m = 32; m; m >>= 1) ss += __shfl_xor(ss, m, 64);
  float r = rsqrtf(ss * (1.0f / 128.0f) + 1e-6f);
  float n1 = v1 * r * w[lane];
  float n2 = v2 * r * w[lane + 64];
  float c = cs[(size_t)bl * 64 + lane];
  float s = sn[(size_t)bl * 64 + lane];
  p[lane]      = (bf16)(n1 * c - n2 * s);
  p[lane + 64] = (bf16)(n1 * s + n2 * c);
}

// ---- causal flash attention: 8 waves x 128 q-rows, swapped QK^T,
//      in-register Q RMSNorm+RoPE (round-16 structure otherwise) ------------
__device__ __forceinline__ void stage_kv8(bf16* Ksb, bf16* Vsb,
                                          const bf16* gK, const bf16* gV,
                                          int kt, int tid) {
#pragma unroll
  for (int i = 0; i < 2; i++) {
    int ck = i * 512 + tid;            // 0..1023
    int kr = ck >> 4, kc = ck & 15;
    gll16(&Ksb[ck * 8], gK + (size_t)(kt * 64 + kr) * EMB + ((kc ^ (kr & 7)) * 8));
    int dr = ck >> 3, vc = ck & 7;
    gll16(&Vsb[ck * 8], gV + (size_t)dr * L_SEQ + kt * 64 + ((vc ^ (dr & 7)) * 8));
  }
}

__global__ __launch_bounds__(512, 2) void fattn_kernel(const bf16* __restrict__ Q,
                                                       const bf16* __restrict__ K,
                                                       const bf16* __restrict__ Vt,
                                                       bf16* __restrict__ AO,
                                                       const float* __restrict__ qw,
                                                       const float* __restrict__ cs,
                                                       const float* __restrict__ sn) {
  __shared__ bf16 Ks[2][64 * 128];   // 32 KB
  __shared__ bf16 Vs[2][64 * 128];   // 32 KB
  __shared__ bf16 Ps[8 * 16 * 64];   // 16 KB, wave-private
  const int tid = threadIdx.x, lane = tid & 63, w = tid >> 6;
  const int l15 = lane & 15, grp = lane >> 4;

  int id = blockIdx.x + blockIdx.y * 16;     // grid (16, 64)
  int bh = id & 63;
  int qt = 15 - (id >> 6);                   // heavy q-tiles first
  const int b = bh >> 4, h = bh & 15;
  const size_t base = (size_t)b * L_SEQ * EMB + h * HD;
  const bf16* gK = K + base;
  const bf16* gV = Vt + (size_t)(b * NH + h) * HD * L_SEQ;
  const int qrow0 = qt * 128 + w * 16;       // wave's 16 q-rows
  const int q_own = qrow0 + l15;

  const float a_ = 0.08838834764831845f * 1.4426950408889634f;
  const float b_ = 12.0f * 1.4426950408889634f;

  // ---- Q load + in-register RMSNorm + RoPE --------------------------------
  // Row q = qrow0+l15 is held by the 4 lanes sharing l15 (grp 0..3); full
  // row sum-of-squares via shfl_xor(16/32). RoPE pairs (d, d+64) are chunks
  // (c, c+2) of the same lane. cos/sin index = bl*64 + (d&63).
  bf16x8 qf[4];
  {
    const bf16* qp = Q + base + (size_t)(qrow0 + l15) * EMB + (grp * 8);
    float qv[4][8];
    float ss = 0.f;
#pragma unroll
    for (int c = 0; c < 4; c++) {
      bf16x8 raw = *(const bf16x8*)(qp + c * 32);
#pragma unroll
      for (int j = 0; j < 8; j++) {
        float v = (float)raw[j];
        qv[c][j] = v;
        ss += v * v;
      }
    }
    ss += __shfl_xor(ss, 16, 64);
    ss += __shfl_xor(ss, 32, 64);
    const float rn = rsqrtf(ss * (1.0f / 128.0f) + 1e-6f);
    const int bl = b * L_SEQ + qrow0 + l15;
    const float* cp = cs + (size_t)bl * 64 + grp * 8;
    const float* sp = sn + (size_t)bl * 64 + grp * 8;
    float cA[8], cB[8], sA[8], sB[8], wv[4][8];
    *(float4*)&cA[0] = *(const float4*)cp;       *(float4*)&cA[4] = *(const float4*)(cp + 4);
    *(float4*)&cB[0] = *(const float4*)(cp + 32); *(float4*)&cB[4] = *(const float4*)(cp + 36);
    *(float4*)&sA[0] = *(const float4*)sp;       *(float4*)&sA[4] = *(const float4*)(sp + 4);
    *(float4*)&sB[0] = *(const float4*)(sp + 32); *(float4*)&sB[4] = *(const float4*)(sp + 36);
#pragma unroll
    for (int c = 0; c < 4; c++) {
      const float* wp = qw + c * 32 + grp * 8;
      *(float4*)&wv[c][0] = *(const float4*)wp;
      *(float4*)&wv[c][4] = *(const float4*)(wp + 4);
    }
#pragma unroll
    for (int j = 0; j < 8; j++) {
      float n0 = qv[0][j] * rn * wv[0][j];
      float n1 = qv[1][j] * rn * wv[1][j];
      float n2 = qv[2][j] * rn * wv[2][j];
      float n3 = qv[3][j] * rn * wv[3][j];
      qf[0][j] = (bf16)(n0 * cA[j] - n2 * sA[j]);
      qf[1][j] = (bf16)(n1 * cB[j] - n3 * sB[j]);
      qf[2][j] = (bf16)(n0 * sA[j] + n2 * cA[j]);
      qf[3][j] = (bf16)(n1 * sB[j] + n3 * cB[j]);
    }
  }

  f32x4 O[8] = {};
  float lsum_p = 0.f;
  bf16* myP = Ps + w * 1024;
  const int pwbase = l15 * 64 + (grp & 1) * 4;
  const int c8base = grp >> 1;

  const int nkt = 2 * qt + 2;
  stage_kv8(Ks[0], Vs[0], gK, gV, 0, tid);
  asm volatile("s_waitcnt vmcnt(0)" ::: "memory");
  __builtin_amdgcn_s_barrier();
  asm volatile("" ::: "memory");

  for (int kt = 0; kt < nkt; kt++) {
    const int cur = kt & 1;
    if (kt + 1 < nkt) stage_kv8(Ks[cur ^ 1], Vs[cur ^ 1], gK, gV, kt + 1, tid);

    if (kt * 64 <= qrow0 + 15) {   // wave-uniform gate
      // S^T = K Q^T
      f32x4 st[4] = {};
      __builtin_amdgcn_s_setprio(1);
#pragma unroll
      for (int s = 0; s < 4; s++) {
        int row = s * 16 + l15;
#pragma unroll
        for (int c = 0; c < 4; c++) {
          int swc = (c * 4 + grp) ^ (row & 7);
          bf16x8 kf = *(const bf16x8*)&Ks[cur][row * 128 + swc * 8];
          st[s] = MFMA16(kf, qf[c], st[s]);
        }
      }
      __builtin_amdgcn_s_setprio(0);

      // bounded-exp P, packed b64 write (mask always)
#pragma unroll
      for (int s = 0; s < 4; s++) {
        float e[4];
#pragma unroll
        for (int r = 0; r < 4; r++) {
          int kg = kt * 64 + s * 16 + grp * 4 + r;
          float v = exp2f(st[s][r] * a_ - b_);
          if (kg > q_own) v = 0.f;
          e[r] = v;
          lsum_p += v;
        }
        bf16x4 pk = {(bf16)e[0], (bf16)e[1], (bf16)e[2], (bf16)e[3]};
        int c8 = s * 2 + c8base;
        *(bf16x4*)&myP[pwbase + ((c8 ^ (l15 & 7)) << 3)] = pk;
      }

      // P read + PV (round-13 proven path)
      bf16x8 pf[2];
#pragma unroll
      for (int kk = 0; kk < 2; kk++) {
        int swc = (kk * 4 + grp) ^ (l15 & 7);
        pf[kk] = *(const bf16x8*)&myP[l15 * 64 + swc * 8];
      }
      __builtin_amdgcn_s_setprio(1);
#pragma unroll
      for (int ni = 0; ni < 8; ni++) {
#pragma unroll
        for (int kk = 0; kk < 2; kk++) {
          int drow = ni * 16 + l15;
          int swc = (kk * 4 + grp) ^ (drow & 7);
          bf16x8 vf = *(const bf16x8*)&Vs[cur][drow * 64 + swc * 8];
          O[ni] = MFMA16(pf[kk], vf, O[ni]);
        }
      }
      __builtin_amdgcn_s_setprio(0);
    }

    asm volatile("s_waitcnt vmcnt(0)" ::: "memory");
    __builtin_amdgcn_s_barrier();
    asm volatile("" ::: "memory");
  }

  // row-sum: reduce partials over the 4 grp lanes, then fetch per output row
  lsum_p += __shfl_xor(lsum_p, 16, 64);
  lsum_p += __shfl_xor(lsum_p, 32, 64);
  float lr[4];
#pragma unroll
  for (int r = 0; r < 4; r++) lr[r] = __shfl(lsum_p, grp * 4 + r, 64);

  const int qg0 = qrow0 + grp * 4;
#pragma unroll
  for (int ni = 0; ni < 8; ni++) {
#pragma unroll
    for (int r = 0; r < 4; r++) {
      float o = O[ni][r] / lr[r];
      AO[(size_t)(b * L_SEQ + qg0 + r) * EMB + h * HD + ni * 16 + l15] = (bf16)o;
    }
  }
}

extern "C" void kernel_launch(void* const* d_in, const int* in_sizes, int n_in,
                              void* d_out, int out_size, void* d_ws, size_t ws_size,
                              hipStream_t stream) {
  const float* x = (const float*)d_in[0];
  const float* cosp = (const float*)d_in[2];
  const float* sinp = (const float*)d_in[3];
  const float* Wq = (const float*)d_in[4];
  const float* Wk = (const float*)d_in[5];
  const float* Wv = (const float*)d_in[6];
  const float* Wo = (const float*)d_in[7];
  const float* qw = (const float*)d_in[8];
  const float* kw = (const float*)d_in[9];

  const size_t ACT = (size_t)BLROWS * EMB * sizeof(bf16);
  const size_t WGT = (size_t)EMB * EMB * sizeof(bf16);
  char* ws = (char*)d_ws;
  bf16* xb    = (bf16*)ws;          ws += ACT;
  bf16* WQKVb = (bf16*)ws;          ws += 3 * WGT;
  bf16* Wob   = (bf16*)ws;          ws += WGT;
  bf16* Qb    = (bf16*)ws;          ws += ACT;
  bf16* Kb    = (bf16*)ws;          ws += ACT;
  bf16* Vtb   = (bf16*)ws;          ws += ACT;
  bf16* AOb   = (bf16*)ws;          ws += ACT;

  f2bAll_kernel<<<dim3(512, 5), 256, 0, stream>>>(
      x, Wq, Wk, Wv, Wo, xb, WQKVb, WQKVb + (size_t)EMB * EMB,
      WQKVb + 2 * (size_t)EMB * EMB, Wob, BLROWS * EMB / 4, EMB * EMB / 4);

  gemm256<0, 256><<<768, 512, 0, stream>>>(xb, WQKVb, Qb, Kb, Vtb, nullptr, EMB);

  normropeK_kernel<<<BLROWS * NH / 4, 256, 0, stream>>>(Kb, kw, cosp, sinp);

  fattn_kernel<<<dim3(16, B_SZ * NH), 512, 0, stream>>>(Qb, Kb, Vtb, AOb,
                                                        qw, cosp, sinp);

  gemm256<1, 128><<<512, 512, 0, stream>>>(AOb, Wob, nullptr, nullptr, nullptr,
                                           (float*)d_out, EMB);
}